// Round 1
// baseline (117.169 us; speedup 1.0000x reference)
//
#include <hip/hip_runtime.h>
#include <math.h>

// Problem dims (fixed by setup_inputs): n=32, t=8, c=128, h=w=32
#define N_  32
#define TC  1024   // t*c channels
#define P_  1024   // h*w pixels
#define KC  64     // int(c*0.5)
#define KT  4      // int(t*0.5)

// workspace layout (float offsets):
//   avg    [0,      32768)   per (n,t,c) spatial mean
//   mx     [32768,  65536)   per (n,t,c) spatial max
//   mask_c [65536,  66560)   int, batch-union channel-topk mask
//   mask_t [66560,  67584)   int, batch-union time-topk mask
//   flag   [67584,  68608)   float XOR mask (im=1)
//   pooled [68608, 199680)   [n][4][pix]: im_avg, im_max, sub_avg, sub_max
//   im_map [199680,232448)   [n][pix]
//   sub_map[232448,265216)   [n][pix]
//   part   [265216,1313792)  [4][n*8][pix] partial channel reductions

// ---------- K0: zero the union masks (must run every call; no stale state) ----
__global__ void k0_zero(int* __restrict__ p) {
    int i = blockIdx.x * 256 + threadIdx.x;
    if (i < 2048) p[i] = 0;
}

// ---------- K1: spatial mean/max per (n,t,c) row of 1024 pixels ---------------
__global__ __launch_bounds__(256) void k1_reduce(const float* __restrict__ x,
                                                 float* __restrict__ avg,
                                                 float* __restrict__ mx) {
    int r = blockIdx.x;                       // r = n*1024 + t*128 + c
    const float4* xp = (const float4*)(x + (size_t)r * P_);
    float4 v = xp[threadIdx.x];
    float s = (v.x + v.y) + (v.z + v.w);
    float m = fmaxf(fmaxf(v.x, v.y), fmaxf(v.z, v.w));
    #pragma unroll
    for (int off = 32; off > 0; off >>= 1) {
        s += __shfl_down(s, off);
        m  = fmaxf(m, __shfl_down(m, off));
    }
    __shared__ float ss[4], sm[4];
    int wid = threadIdx.x >> 6, lane = threadIdx.x & 63;
    if (lane == 0) { ss[wid] = s; sm[wid] = m; }
    __syncthreads();
    if (threadIdx.x == 0) {
        float ts = (ss[0] + ss[1]) + (ss[2] + ss[3]);
        float tm = fmaxf(fmaxf(sm[0], sm[1]), fmaxf(sm[2], sm[3]));
        avg[r] = ts * (1.0f / 1024.0f);
        mx[r]  = tm;
    }
}

// ---------- K2: map_add + fc + exact top-k rank masks (one block per n) -------
__global__ __launch_bounds__(256) void k2_map(const float* __restrict__ avg,
                                              const float* __restrict__ mx,
                                              const float* __restrict__ alpha,
                                              const float* __restrict__ beta,
                                              const float* __restrict__ wfc,
                                              int* __restrict__ mask_c,
                                              int* __restrict__ mask_t) {
    __shared__ float m[TC], mf[TC], w[64];
    int n = blockIdx.x;
    float a0 = alpha[0], b0 = beta[0];
    if (threadIdx.x < 64) w[threadIdx.x] = wfc[threadIdx.x];
    for (int i = threadIdx.x; i < TC; i += 256) {
        float a = avg[n * TC + i], b = mx[n * TC + i];
        m[i] = 0.5f * (a + b) + a0 * a + b0 * b;
    }
    __syncthreads();
    // fc along time: mf[s*128+c] = sum_t m[t*128+c] * W[s][t]
    for (int i = threadIdx.x; i < TC; i += 256) {
        int s = i >> 7, cc = i & 127;
        float acc = 0.0f;
        #pragma unroll
        for (int tt = 0; tt < 8; ++tt) acc += m[tt * 128 + cc] * w[s * 8 + tt];
        mf[i] = acc;
    }
    __syncthreads();
    // exact lax.top_k emulation: selected iff
    //   #{j: v_j > v_i} + #{j: v_j == v_i && j < i} < k
    for (int i = threadIdx.x; i < TC; i += 256) {
        int tt = i >> 7, cc = i & 127;
        float v = mf[i];
        int rc = 0;
        for (int c2 = 0; c2 < 128; ++c2) {
            float u = mf[tt * 128 + c2];
            rc += (u > v) || (u == v && c2 < cc);
        }
        if (rc < KC) mask_c[i] = 1;   // benign race: all writers store 1
        int rt = 0;
        #pragma unroll
        for (int t2 = 0; t2 < 8; ++t2) {
            float u = mf[t2 * 128 + cc];
            rt += (u > v) || (u == v && t2 < tt);
        }
        if (rt < KT) mask_t[i] = 1;
    }
}

// ---------- K3: XOR the masks -> float flag ----------------------------------
__global__ void k3_flag(const int* __restrict__ mc, const int* __restrict__ mt,
                        float* __restrict__ flag) {
    int i = blockIdx.x * 256 + threadIdx.x;
    if (i < TC) flag[i] = ((mc[i] != 0) != (mt[i] != 0)) ? 1.0f : 0.0f;
}

// ---------- K4: masked channel partial sums/maxes per (n, chan-group, pixel) --
__global__ __launch_bounds__(1024) void k4_partial(const float* __restrict__ x,
                                                   const float* __restrict__ flag,
                                                   float* __restrict__ part) {
    __shared__ float sf[TC];
    sf[threadIdx.x] = flag[threadIdx.x];
    __syncthreads();
    int n = blockIdx.x >> 3, g = blockIdx.x & 7;
    const float* xb = x + (((size_t)n * TC + g * 128) * P_) + threadIdx.x;
    float ims = 0.0f, subs = 0.0f, imm = -INFINITY, subm = -INFINITY;
    for (int k = 0; k < 128; ++k) {
        float v = xb[(size_t)k * P_];
        bool im = sf[g * 128 + k] != 0.0f;
        float iv = im ? v : 0.0f;   // imf includes zeros at masked-out slots
        float sv = im ? 0.0f : v;
        ims += iv;  imm  = fmaxf(imm, iv);
        subs += sv; subm = fmaxf(subm, sv);
    }
    size_t base = (size_t)blockIdx.x * P_ + threadIdx.x;
    part[base]          = ims;
    part[base + 262144] = imm;
    part[base + 524288] = subs;
    part[base + 786432] = subm;
}

// ---------- K5a: combine 8 channel-groups -> pooled stats ---------------------
__global__ void k5_combine(const float* __restrict__ part,
                           float* __restrict__ pooled) {
    int id = blockIdx.x * 256 + threadIdx.x;       // 0..32767
    int n = id >> 10, pix = id & 1023;
    float s_im = 0.0f, m_im = -INFINITY, s_sub = 0.0f, m_sub = -INFINITY;
    #pragma unroll
    for (int g = 0; g < 8; ++g) {
        size_t b = (size_t)(n * 8 + g) * P_ + pix;
        s_im  += part[b];
        m_im   = fmaxf(m_im, part[b + 262144]);
        s_sub += part[b + 524288];
        m_sub  = fmaxf(m_sub, part[b + 786432]);
    }
    float* pb = pooled + (size_t)n * 4 * P_;
    pb[0 * P_ + pix] = (s_im  / 1024.0f) / 0.5f;   // mean / LAM
    pb[1 * P_ + pix] = m_im;
    pb[2 * P_ + pix] = (s_sub / 1024.0f) / 0.5f;   // mean / (1-LAM)
    pb[3 * P_ + pix] = m_sub;
}

// ---------- K5b: 3x3 SAME conv (2ch->1) + sigmoid, for both maps --------------
__global__ __launch_bounds__(1024) void k5_conv(const float* __restrict__ pooled,
                                                const float* __restrict__ w1,
                                                const float* __restrict__ w2,
                                                float* __restrict__ im_map,
                                                float* __restrict__ sub_map) {
    int n = blockIdx.x, pix = threadIdx.x;
    int y = pix >> 5, xx = pix & 31;
    const float* pb = pooled + (size_t)n * 4 * P_;
    float acc1 = 0.0f, acc2 = 0.0f;
    #pragma unroll
    for (int i = 0; i < 2; ++i)
        #pragma unroll
        for (int dy = 0; dy < 3; ++dy) {
            int yy = y + dy - 1;
            if (yy < 0 || yy >= 32) continue;
            #pragma unroll
            for (int dx = 0; dx < 3; ++dx) {
                int xc = xx + dx - 1;
                if (xc < 0 || xc >= 32) continue;
                acc1 += pb[i * P_ + yy * 32 + xc]       * w1[i * 9 + dy * 3 + dx];
                acc2 += pb[(2 + i) * P_ + yy * 32 + xc] * w2[i * 9 + dy * 3 + dx];
            }
        }
    im_map[n * P_ + pix]  = 1.0f / (1.0f + expf(-acc1));
    sub_map[n * P_ + pix] = 1.0f / (1.0f + expf(-acc2));
}

// ---------- K6: out = x * (flag ? im_map : sub_map), float4 streaming ---------
__global__ __launch_bounds__(256) void k6_out(const float* __restrict__ x,
                                              const float* __restrict__ flag,
                                              const float* __restrict__ im_map,
                                              const float* __restrict__ sub_map,
                                              float* __restrict__ out) {
    size_t i4 = (size_t)blockIdx.x * 256 + threadIdx.x;   // float4 index
    size_t e = i4 * 4;
    int n   = (int)(e >> 20);           // / (1024*1024)
    int rem = (int)(e & 1048575);
    int ch  = rem >> 10;
    int pix = rem & 1023;               // multiple of 4
    float4 xv = ((const float4*)x)[i4];
    bool im = flag[ch] != 0.0f;
    const float* mp = (im ? im_map : sub_map) + (size_t)n * P_ + pix;
    float4 mv = *(const float4*)mp;
    float4 o;
    o.x = xv.x * mv.x; o.y = xv.y * mv.y; o.z = xv.z * mv.z; o.w = xv.w * mv.w;
    ((float4*)out)[i4] = o;
}

extern "C" void kernel_launch(void* const* d_in, const int* in_sizes, int n_in,
                              void* d_out, int out_size, void* d_ws, size_t ws_size,
                              hipStream_t stream) {
    const float* x     = (const float*)d_in[0];
    const float* alpha = (const float*)d_in[1];
    const float* beta  = (const float*)d_in[2];
    const float* wfc   = (const float*)d_in[3];
    const float* w1    = (const float*)d_in[4];
    const float* w2    = (const float*)d_in[5];
    float* out = (float*)d_out;
    float* ws  = (float*)d_ws;

    float* avg     = ws;
    float* mx      = ws + 32768;
    int*   mask_c  = (int*)(ws + 65536);   // mask_t contiguous after it
    int*   mask_t  = (int*)(ws + 66560);
    float* flag    = ws + 67584;
    float* pooled  = ws + 68608;
    float* im_map  = ws + 199680;
    float* sub_map = ws + 232448;
    float* part    = ws + 265216;

    k0_zero   <<<8,     256, 0, stream>>>(mask_c);            // zeros both masks
    k1_reduce <<<32768, 256, 0, stream>>>(x, avg, mx);
    k2_map    <<<32,    256, 0, stream>>>(avg, mx, alpha, beta, wfc, mask_c, mask_t);
    k3_flag   <<<4,     256, 0, stream>>>(mask_c, mask_t, flag);
    k4_partial<<<256,  1024, 0, stream>>>(x, flag, part);
    k5_combine<<<128,   256, 0, stream>>>(part, pooled);
    k5_conv   <<<32,   1024, 0, stream>>>(pooled, w1, w2, im_map, sub_map);
    k6_out    <<<32768, 256, 0, stream>>>(x, flag, im_map, sub_map, out);
}

// Round 2
// 115.716 us; speedup vs baseline: 1.0126x; 1.0126x over previous
//
#include <hip/hip_runtime.h>
#include <math.h>

// Problem dims (fixed by setup_inputs): n=32, t=8, c=128, h=w=32
#define TC  1024   // t*c channels
#define P_  1024   // h*w pixels
#define KC  64     // int(c*0.5)
#define KT  4      // int(t*0.5)

// workspace layout (float offsets):
//   avg    [0,      32768)    per (n,t,c) spatial mean
//   mx     [32768,  65536)    per (n,t,c) spatial max
//   mask_c [65536,  66560)    int, batch-union channel-topk mask
//   mask_t [66560,  67584)    int, batch-union time-topk mask
//   flag   [67584,  68608)    float XOR mask (im=1)
//   im_map [68608,  101376)   [n][pix]
//   sub_map[101376, 134144)   [n][pix]
//   part   [134144, 4328448)  4 planes of [1024 rows][1024 floats]

// ---------- K1: spatial mean/max per (n,t,c); block 0 also zeros the masks ---
__global__ __launch_bounds__(256) void k1_reduce(const float* __restrict__ x,
                                                 float* __restrict__ avg,
                                                 float* __restrict__ mx,
                                                 int* __restrict__ masks) {
    int r = blockIdx.x;                       // r = n*1024 + t*128 + c
    if (r == 0) {                             // zero mask_c+mask_t (2048 ints)
        #pragma unroll
        for (int j = 0; j < 8; ++j) masks[j * 256 + threadIdx.x] = 0;
    }
    const float4* xp = (const float4*)(x + (size_t)r * P_);
    float4 v = xp[threadIdx.x];
    float s = (v.x + v.y) + (v.z + v.w);
    float m = fmaxf(fmaxf(v.x, v.y), fmaxf(v.z, v.w));
    #pragma unroll
    for (int off = 32; off > 0; off >>= 1) {
        s += __shfl_down(s, off);
        m  = fmaxf(m, __shfl_down(m, off));
    }
    __shared__ float ss[4], sm[4];
    int wid = threadIdx.x >> 6, lane = threadIdx.x & 63;
    if (lane == 0) { ss[wid] = s; sm[wid] = m; }
    __syncthreads();
    if (threadIdx.x == 0) {
        float ts = (ss[0] + ss[1]) + (ss[2] + ss[3]);
        float tm = fmaxf(fmaxf(sm[0], sm[1]), fmaxf(sm[2], sm[3]));
        avg[r] = ts * (1.0f / 1024.0f);
        mx[r]  = tm;
    }
}

// ---------- K2: map_add + fc + exact top-k rank masks (one block per n) -------
__global__ __launch_bounds__(256) void k2_map(const float* __restrict__ avg,
                                              const float* __restrict__ mx,
                                              const float* __restrict__ alpha,
                                              const float* __restrict__ beta,
                                              const float* __restrict__ wfc,
                                              int* __restrict__ mask_c,
                                              int* __restrict__ mask_t) {
    __shared__ float m[TC], mf[TC], w[64];
    int n = blockIdx.x;
    float a0 = alpha[0], b0 = beta[0];
    if (threadIdx.x < 64) w[threadIdx.x] = wfc[threadIdx.x];
    for (int i = threadIdx.x; i < TC; i += 256) {
        float a = avg[n * TC + i], b = mx[n * TC + i];
        m[i] = 0.5f * (a + b) + a0 * a + b0 * b;
    }
    __syncthreads();
    // fc along time: mf[s*128+c] = sum_t m[t*128+c] * W[s][t]
    for (int i = threadIdx.x; i < TC; i += 256) {
        int s = i >> 7, cc = i & 127;
        float acc = 0.0f;
        #pragma unroll
        for (int tt = 0; tt < 8; ++tt) acc += m[tt * 128 + cc] * w[s * 8 + tt];
        mf[i] = acc;
    }
    __syncthreads();
    // exact lax.top_k emulation: selected iff
    //   #{j: v_j > v_i} + #{j: v_j == v_i && j < i} < k
    for (int i = threadIdx.x; i < TC; i += 256) {
        int tt = i >> 7, cc = i & 127;
        float v = mf[i];
        int rc = 0;
        #pragma unroll 16
        for (int c2 = 0; c2 < 128; ++c2) {
            float u = mf[tt * 128 + c2];
            rc += (u > v) || (u == v && c2 < cc);
        }
        if (rc < KC) mask_c[i] = 1;   // benign race: all writers store 1
        int rt = 0;
        #pragma unroll
        for (int t2 = 0; t2 < 8; ++t2) {
            float u = mf[t2 * 128 + cc];
            rt += (u > v) || (u == v && t2 < tt);
        }
        if (rt < KT) mask_t[i] = 1;
    }
}

// ---------- K4: masked channel partial stats, float4, k-split 4 ways ----------
// block b = ((n*8 + g)*4 + kq); 256 threads = 256 float4 pixel lanes;
// covers channels g*128 + kq*32 .. +31. Also computes the XOR flag per block
// (n==0,kq==0 blocks publish it to global for K6).
__global__ __launch_bounds__(256) void k4_partial(const float* __restrict__ x,
                                                  const int* __restrict__ mask_c,
                                                  const int* __restrict__ mask_t,
                                                  float* __restrict__ flag_out,
                                                  float* __restrict__ part) {
    int b = blockIdx.x;
    int kq = b & 3, g = (b >> 2) & 7, n = b >> 5;
    __shared__ float sf[128];
    if (threadIdx.x < 128) {
        int ch = g * 128 + threadIdx.x;
        float f = ((mask_c[ch] != 0) != (mask_t[ch] != 0)) ? 1.0f : 0.0f;
        sf[threadIdx.x] = f;
        if (n == 0 && kq == 0) flag_out[ch] = f;
    }
    __syncthreads();
    const float4* xb = (const float4*)x
                     + ((size_t)(n * TC + g * 128 + kq * 32) * 256) + threadIdx.x;
    float4 ims  = {0.f, 0.f, 0.f, 0.f};
    float4 subs = {0.f, 0.f, 0.f, 0.f};
    float4 imm  = {-INFINITY, -INFINITY, -INFINITY, -INFINITY};
    float4 subm = {-INFINITY, -INFINITY, -INFINITY, -INFINITY};
    #pragma unroll 8
    for (int k = 0; k < 32; ++k) {
        float4 v = xb[(size_t)k * 256];
        float f = sf[kq * 32 + k];
        float iv;
        iv = v.x * f; ims.x += iv; imm.x = fmaxf(imm.x, iv);
        v.x -= iv;    subs.x += v.x; subm.x = fmaxf(subm.x, v.x);
        iv = v.y * f; ims.y += iv; imm.y = fmaxf(imm.y, iv);
        v.y -= iv;    subs.y += v.y; subm.y = fmaxf(subm.y, v.y);
        iv = v.z * f; ims.z += iv; imm.z = fmaxf(imm.z, iv);
        v.z -= iv;    subs.z += v.z; subm.z = fmaxf(subm.z, v.z);
        iv = v.w * f; ims.w += iv; imm.w = fmaxf(imm.w, iv);
        v.w -= iv;    subs.w += v.w; subm.w = fmaxf(subm.w, v.w);
    }
    float4* pp = (float4*)part + (size_t)b * 256 + threadIdx.x;
    pp[0]      = ims;    // plane stride = 1024 rows * 256 float4 = 262144
    pp[262144] = imm;
    pp[524288] = subs;
    pp[786432] = subm;
}

// ---------- K5: combine 32 partials -> pooled (LDS) -> 3x3 conv + sigmoid -----
__global__ __launch_bounds__(1024) void k5_conv(const float* __restrict__ part,
                                                const float* __restrict__ w1,
                                                const float* __restrict__ w2,
                                                float* __restrict__ im_map,
                                                float* __restrict__ sub_map) {
    __shared__ float sp[4][P_];
    int n = blockIdx.x, p = threadIdx.x;
    float s_im = 0.f, s_sub = 0.f, m_im = -INFINITY, m_sub = -INFINITY;
    #pragma unroll 8
    for (int gk = 0; gk < 32; ++gk) {
        size_t idx = ((size_t)(n * 32 + gk)) * P_ + p;
        s_im  += part[idx];
        m_im   = fmaxf(m_im, part[idx + 1048576]);
        s_sub += part[idx + 2097152];
        m_sub  = fmaxf(m_sub, part[idx + 3145728]);
    }
    sp[0][p] = (s_im  * (1.0f / 1024.0f)) / 0.5f;   // im_avg / LAM
    sp[1][p] = m_im;
    sp[2][p] = (s_sub * (1.0f / 1024.0f)) / 0.5f;   // sub_avg / (1-LAM)
    sp[3][p] = m_sub;
    __syncthreads();
    int y = p >> 5, xx = p & 31;
    float acc1 = 0.0f, acc2 = 0.0f;
    #pragma unroll
    for (int i = 0; i < 2; ++i)
        #pragma unroll
        for (int dy = 0; dy < 3; ++dy) {
            int yy = y + dy - 1;
            if (yy < 0 || yy >= 32) continue;
            #pragma unroll
            for (int dx = 0; dx < 3; ++dx) {
                int xc = xx + dx - 1;
                if (xc < 0 || xc >= 32) continue;
                acc1 += sp[i][yy * 32 + xc]     * w1[i * 9 + dy * 3 + dx];
                acc2 += sp[2 + i][yy * 32 + xc] * w2[i * 9 + dy * 3 + dx];
            }
        }
    im_map[n * P_ + p]  = 1.0f / (1.0f + expf(-acc1));
    sub_map[n * P_ + p] = 1.0f / (1.0f + expf(-acc2));
}

// ---------- K6: out = x * (flag ? im_map : sub_map), float4 streaming ---------
__global__ __launch_bounds__(256) void k6_out(const float* __restrict__ x,
                                              const float* __restrict__ flag,
                                              const float* __restrict__ im_map,
                                              const float* __restrict__ sub_map,
                                              float* __restrict__ out) {
    size_t i4 = (size_t)blockIdx.x * 256 + threadIdx.x;   // float4 index
    size_t e = i4 * 4;
    int n   = (int)(e >> 20);           // / (1024*1024)
    int rem = (int)(e & 1048575);
    int ch  = rem >> 10;
    int pix = rem & 1023;               // multiple of 4
    float4 xv = ((const float4*)x)[i4];
    bool im = flag[ch] != 0.0f;
    const float* mp = (im ? im_map : sub_map) + (size_t)n * P_ + pix;
    float4 mv = *(const float4*)mp;
    float4 o;
    o.x = xv.x * mv.x; o.y = xv.y * mv.y; o.z = xv.z * mv.z; o.w = xv.w * mv.w;
    ((float4*)out)[i4] = o;
}

extern "C" void kernel_launch(void* const* d_in, const int* in_sizes, int n_in,
                              void* d_out, int out_size, void* d_ws, size_t ws_size,
                              hipStream_t stream) {
    const float* x     = (const float*)d_in[0];
    const float* alpha = (const float*)d_in[1];
    const float* beta  = (const float*)d_in[2];
    const float* wfc   = (const float*)d_in[3];
    const float* w1    = (const float*)d_in[4];
    const float* w2    = (const float*)d_in[5];
    float* out = (float*)d_out;
    float* ws  = (float*)d_ws;

    float* avg     = ws;
    float* mx      = ws + 32768;
    int*   mask_c  = (int*)(ws + 65536);   // mask_t contiguous after it
    int*   mask_t  = (int*)(ws + 66560);
    float* flag    = ws + 67584;
    float* im_map  = ws + 68608;
    float* sub_map = ws + 101376;
    float* part    = ws + 134144;

    k1_reduce <<<32768, 256, 0, stream>>>(x, avg, mx, mask_c);
    k2_map    <<<32,    256, 0, stream>>>(avg, mx, alpha, beta, wfc, mask_c, mask_t);
    k4_partial<<<1024,  256, 0, stream>>>(x, mask_c, mask_t, flag, part);
    k5_conv   <<<32,   1024, 0, stream>>>(part, w1, w2, im_map, sub_map);
    k6_out    <<<32768, 256, 0, stream>>>(x, flag, im_map, sub_map, out);
}

// Round 5
// 96.589 us; speedup vs baseline: 1.2131x; 1.1980x over previous
//
#include <hip/hip_runtime.h>
#include <math.h>

// Problem dims (fixed by setup_inputs): n=32, t=8, c=128, h=w=32
#define TC  1024   // t*c channels
#define P_  1024   // h*w pixels
#define KC  64     // int(c*0.5)
#define KT  4      // int(t*0.5)

typedef float vfloat4 __attribute__((ext_vector_type(4)));   // native vec for NT store

// workspace layout (float offsets):
//   avg    [0,      32768)    per (n,t,c) spatial mean
//   mx     [32768,  65536)    per (n,t,c) spatial max
//   mask_c [65536,  66560)    int, batch-union channel-topk mask
//   mask_t [66560,  67584)    int, batch-union time-topk mask
//   flag   [67584,  68608)    float XOR mask (im=1)
//   im_map [68608,  101376)   [n][pix]
//   sub_map[101376, 134144)   [n][pix]
//   part   [134144, 658432)   [cq=4][n=32][stat=4][pix=1024] pooled partials

// ---------- K1: spatial mean/max per (n,t,c); block 0 also zeros the masks ---
__global__ __launch_bounds__(256) void k1_reduce(const float* __restrict__ x,
                                                 float* __restrict__ avg,
                                                 float* __restrict__ mx,
                                                 int* __restrict__ masks) {
    int r = blockIdx.x;                       // r = n*1024 + t*128 + c
    if (r == 0) {                             // zero mask_c+mask_t (2048 ints)
        #pragma unroll
        for (int j = 0; j < 8; ++j) masks[j * 256 + threadIdx.x] = 0;
    }
    const float4* xp = (const float4*)(x + (size_t)r * P_);
    float4 v = xp[threadIdx.x];
    float s = (v.x + v.y) + (v.z + v.w);
    float m = fmaxf(fmaxf(v.x, v.y), fmaxf(v.z, v.w));
    #pragma unroll
    for (int off = 32; off > 0; off >>= 1) {
        s += __shfl_down(s, off);
        m  = fmaxf(m, __shfl_down(m, off));
    }
    __shared__ float ss[4], sm[4];
    int wid = threadIdx.x >> 6, lane = threadIdx.x & 63;
    if (lane == 0) { ss[wid] = s; sm[wid] = m; }
    __syncthreads();
    if (threadIdx.x == 0) {
        float ts = (ss[0] + ss[1]) + (ss[2] + ss[3]);
        float tm = fmaxf(fmaxf(sm[0], sm[1]), fmaxf(sm[2], sm[3]));
        avg[r] = ts * (1.0f / 1024.0f);
        mx[r]  = tm;
    }
}

// ---------- K2: map_add + fc + exact top-k rank masks; block = (n, tt) -------
__global__ __launch_bounds__(256) void k2_map(const float* __restrict__ avg,
                                              const float* __restrict__ mx,
                                              const float* __restrict__ alpha,
                                              const float* __restrict__ beta,
                                              const float* __restrict__ wfc,
                                              int* __restrict__ mask_c,
                                              int* __restrict__ mask_t) {
    __shared__ float m[TC], mf[TC], w[64];
    int n = blockIdx.x >> 3, tt = blockIdx.x & 7;
    float a0 = alpha[0], b0 = beta[0];
    if (threadIdx.x < 64) w[threadIdx.x] = wfc[threadIdx.x];
    for (int i = threadIdx.x; i < TC; i += 256) {
        float a = avg[n * TC + i], b = mx[n * TC + i];
        m[i] = 0.5f * (a + b) + a0 * a + b0 * b;
    }
    __syncthreads();
    // fc along time: mf[s*128+c] = sum_t m[t*128+c] * W[s][t]
    for (int i = threadIdx.x; i < TC; i += 256) {
        int s = i >> 7, cc = i & 127;
        float acc = 0.0f;
        #pragma unroll
        for (int t2 = 0; t2 < 8; ++t2) acc += m[t2 * 128 + cc] * w[s * 8 + t2];
        mf[i] = acc;
    }
    __syncthreads();
    // exact lax.top_k emulation for row tt: selected iff
    //   #{j: v_j > v_i} + #{j: v_j == v_i && j < i} < k
    if (threadIdx.x < 128) {
        int cc = threadIdx.x, i = tt * 128 + cc;
        float v = mf[i];
        int rc = 0;
        #pragma unroll 16
        for (int c2 = 0; c2 < 128; ++c2) {
            float u = mf[tt * 128 + c2];
            rc += (u > v) || (u == v && c2 < cc);
        }
        if (rc < KC) mask_c[i] = 1;   // benign race: all writers store 1
        int rt = 0;
        #pragma unroll
        for (int t2 = 0; t2 < 8; ++t2) {
            float u = mf[t2 * 128 + cc];
            rt += (u > v) || (u == v && t2 < tt);
        }
        if (rt < KT) mask_t[i] = 1;
    }
}

// ---------- K4: masked channel stats; block = (n, pix-quarter, chan-quarter) --
// 512 blocks x 256 thr. Thread (cg = tid>>6, l = tid&63) accumulates 64
// channels for float4-pixel pq*64+l; LDS-reduce across the 4 cg subgroups;
// write pooled partials [cq][n][stat][pix].
__global__ __launch_bounds__(256) void k4_partial(const float* __restrict__ x,
                                                  const int* __restrict__ mask_c,
                                                  const int* __restrict__ mask_t,
                                                  float* __restrict__ flag_out,
                                                  float* __restrict__ part) {
    int b = blockIdx.x;
    int cq = b & 3, pq = (b >> 2) & 3, n = b >> 4;
    __shared__ float sf[256];
    __shared__ float4 red[4][4][64];   // [stat][cg][l]
    {
        int i = threadIdx.x;
        int ch = cq * 256 + i;
        float f = ((mask_c[ch] != 0) != (mask_t[ch] != 0)) ? 1.0f : 0.0f;
        sf[i] = f;
        if (n == 0 && pq == 0) flag_out[ch] = f;
    }
    __syncthreads();
    int l = threadIdx.x & 63, cg = threadIdx.x >> 6;
    int f4p = pq * 64 + l;
    int ch0 = cq * 256 + cg * 64;
    const float4* xb = (const float4*)x + ((size_t)(n * TC + ch0)) * 256 + f4p;
    float4 ims  = {0.f, 0.f, 0.f, 0.f};
    float4 subs = {0.f, 0.f, 0.f, 0.f};
    float4 imm  = {-INFINITY, -INFINITY, -INFINITY, -INFINITY};
    float4 subm = {-INFINITY, -INFINITY, -INFINITY, -INFINITY};
    #pragma unroll 8
    for (int k = 0; k < 64; ++k) {
        float4 v = xb[(size_t)k * 256];
        float f = sf[cg * 64 + k];
        float iv;
        iv = v.x * f; ims.x += iv; imm.x = fmaxf(imm.x, iv);
        v.x -= iv;    subs.x += v.x; subm.x = fmaxf(subm.x, v.x);
        iv = v.y * f; ims.y += iv; imm.y = fmaxf(imm.y, iv);
        v.y -= iv;    subs.y += v.y; subm.y = fmaxf(subm.y, v.y);
        iv = v.z * f; ims.z += iv; imm.z = fmaxf(imm.z, iv);
        v.z -= iv;    subs.z += v.z; subm.z = fmaxf(subm.z, v.z);
        iv = v.w * f; ims.w += iv; imm.w = fmaxf(imm.w, iv);
        v.w -= iv;    subs.w += v.w; subm.w = fmaxf(subm.w, v.w);
    }
    red[0][cg][l] = ims;
    red[1][cg][l] = imm;
    red[2][cg][l] = subs;
    red[3][cg][l] = subm;
    __syncthreads();
    if (threadIdx.x < 64) {
        float4 s0 = red[0][0][l], s1 = red[1][0][l], s2 = red[2][0][l], s3 = red[3][0][l];
        #pragma unroll
        for (int g = 1; g < 4; ++g) {
            float4 a = red[0][g][l], bq = red[1][g][l], c = red[2][g][l], d = red[3][g][l];
            s0.x += a.x; s0.y += a.y; s0.z += a.z; s0.w += a.w;
            s1.x = fmaxf(s1.x, bq.x); s1.y = fmaxf(s1.y, bq.y);
            s1.z = fmaxf(s1.z, bq.z); s1.w = fmaxf(s1.w, bq.w);
            s2.x += c.x; s2.y += c.y; s2.z += c.z; s2.w += c.w;
            s3.x = fmaxf(s3.x, d.x); s3.y = fmaxf(s3.y, d.y);
            s3.z = fmaxf(s3.z, d.z); s3.w = fmaxf(s3.w, d.w);
        }
        float4* pp = (float4*)part + ((size_t)(cq * 32 + n) * 4) * 256 + f4p;
        pp[0]   = s0;
        pp[256] = s1;
        pp[512] = s2;
        pp[768] = s3;
    }
}

// ---------- K5: combine 4 chan-quarters -> pooled (LDS) -> 3x3 conv + sigmoid -
__global__ __launch_bounds__(1024) void k5_conv(const float* __restrict__ part,
                                                const float* __restrict__ w1,
                                                const float* __restrict__ w2,
                                                float* __restrict__ im_map,
                                                float* __restrict__ sub_map) {
    __shared__ float sp[4][P_];
    int n = blockIdx.x, p = threadIdx.x;
    float s_im = 0.f, s_sub = 0.f, m_im = -INFINITY, m_sub = -INFINITY;
    #pragma unroll
    for (int q = 0; q < 4; ++q) {
        size_t base = ((size_t)(q * 32 + n) * 4) * P_ + p;
        s_im  += part[base];
        m_im   = fmaxf(m_im, part[base + 1024]);
        s_sub += part[base + 2048];
        m_sub  = fmaxf(m_sub, part[base + 3072]);
    }
    sp[0][p] = s_im  * (2.0f / 1024.0f);   // mean / LAM
    sp[1][p] = m_im;
    sp[2][p] = s_sub * (2.0f / 1024.0f);   // mean / (1-LAM)
    sp[3][p] = m_sub;
    __syncthreads();
    int y = p >> 5, xx = p & 31;
    float acc1 = 0.0f, acc2 = 0.0f;
    #pragma unroll
    for (int i = 0; i < 2; ++i)
        #pragma unroll
        for (int dy = 0; dy < 3; ++dy) {
            int yy = y + dy - 1;
            if (yy < 0 || yy >= 32) continue;
            #pragma unroll
            for (int dx = 0; dx < 3; ++dx) {
                int xc = xx + dx - 1;
                if (xc < 0 || xc >= 32) continue;
                acc1 += sp[i][yy * 32 + xc]     * w1[i * 9 + dy * 3 + dx];
                acc2 += sp[2 + i][yy * 32 + xc] * w2[i * 9 + dy * 3 + dx];
            }
        }
    im_map[n * P_ + p]  = 1.0f / (1.0f + expf(-acc1));
    sub_map[n * P_ + p] = 1.0f / (1.0f + expf(-acc2));
}

// ---------- K6: out = x * (flag ? im_map : sub_map); 4 float4/thr, NT stores --
// g = global thread id; n = g>>16; rem = g&65535 -> ch = rem>>8, pixf4 = rem&255.
// j-step adds 256 channels (65536 float4) within the same n; full coverage of
// [0, 262144) float4 per n, same map pixel for all 4 steps.
__global__ __launch_bounds__(256) void k6_out(const float* __restrict__ x,
                                              const float* __restrict__ flag,
                                              const float* __restrict__ im_map,
                                              const float* __restrict__ sub_map,
                                              float* __restrict__ out) {
    int g   = blockIdx.x * 256 + threadIdx.x;   // 0 .. 2097151
    int n   = g >> 16;
    int rem = g & 65535;
    int ch    = rem >> 8;                       // 0..255 (channel row base)
    int pixf4 = rem & 255;
    size_t base = ((size_t)n << 18) + rem;      // float4 index
    const float4* xp = (const float4*)x + base;
    const float4* imb  = (const float4*)im_map  + n * 256 + pixf4;
    const float4* subb = (const float4*)sub_map + n * 256 + pixf4;
    float4 im_v  = *imb;
    float4 sub_v = *subb;
    #pragma unroll
    for (int j = 0; j < 4; ++j) {
        float4 xv = xp[j * 65536];              // +256 channels, same pixel
        bool im = flag[ch + j * 256] != 0.0f;
        float4 mv = im ? im_v : sub_v;
        vfloat4 o;
        o.x = xv.x * mv.x; o.y = xv.y * mv.y; o.z = xv.z * mv.z; o.w = xv.w * mv.w;
        __builtin_nontemporal_store(o, (vfloat4*)out + base + (size_t)j * 65536);
    }
}

extern "C" void kernel_launch(void* const* d_in, const int* in_sizes, int n_in,
                              void* d_out, int out_size, void* d_ws, size_t ws_size,
                              hipStream_t stream) {
    const float* x     = (const float*)d_in[0];
    const float* alpha = (const float*)d_in[1];
    const float* beta  = (const float*)d_in[2];
    const float* wfc   = (const float*)d_in[3];
    const float* w1    = (const float*)d_in[4];
    const float* w2    = (const float*)d_in[5];
    float* out = (float*)d_out;
    float* ws  = (float*)d_ws;

    float* avg     = ws;
    float* mx      = ws + 32768;
    int*   mask_c  = (int*)(ws + 65536);   // mask_t contiguous after it
    int*   mask_t  = (int*)(ws + 66560);
    float* flag    = ws + 67584;
    float* im_map  = ws + 68608;
    float* sub_map = ws + 101376;
    float* part    = ws + 134144;

    k1_reduce <<<32768, 256, 0, stream>>>(x, avg, mx, mask_c);
    k2_map    <<<256,   256, 0, stream>>>(avg, mx, alpha, beta, wfc, mask_c, mask_t);
    k4_partial<<<512,   256, 0, stream>>>(x, mask_c, mask_t, flag, part);
    k5_conv   <<<32,   1024, 0, stream>>>(part, w1, w2, im_map, sub_map);
    k6_out    <<<8192,  256, 0, stream>>>(x, flag, im_map, sub_map, out);
}